// Round 4
// baseline (387.918 us; speedup 1.0000x reference)
//
#include <hip/hip_runtime.h>

typedef __bf16 bf16;
typedef __bf16 bf16x4 __attribute__((ext_vector_type(4)));
typedef __bf16 bf16x8 __attribute__((ext_vector_type(8)));
typedef float  f32x4  __attribute__((ext_vector_type(4)));

// Problem constants
#define NB    16384      // batch
#define NOBS  568
#define NH    256
#define NAG   19         // N_OTHER

// ws byte offsets (all 16B aligned)
#define OFF_WT_MU    0u          // CHUNK-MAJOR [18][256][32] bf16
#define OFF_WT_VAR   294912u     // CHUNK-MAJOR [18][256][32]
#define OFF_WT_SELF  589824u     // CHUNK-MAJOR [2][256][32]
#define OFF_WT_OTHER 622592u     // [256][32]  (chunk-major == flat at K=32)
#define OFF_WT_Q     638976u     // CHUNK-MAJOR [8][256][32] (chunk-8 overflow -> WT_K)
#define OFF_WT_K     770048u     // CHUNK-MAJOR [8][256][32]  (K chunk-8 overflow lands here)
#define OFF_WT_V1    901120u     // CHUNK-MAJOR [8][256][32]  (V1 chunk-8 overflow lands here)
#define OFF_WT_V2    1032192u    // CHUNK-MAJOR [8][256][32] (chunk-8 overflow -> WT_A1)
#define OFF_WT_A1    1163264u    // flat [256][256] (dualA stages via LDS)
#define OFF_WT_A2    1294336u    // flat
#define OFF_Z        1425408u    // UNUSED since round 14 (z lives in LDS only)
#define OFF_SELF     9814016u
#define OFF_Q        18202624u
#define OFF_SV       26591232u   // bf16 (includes b_v)
#define OFF_H        34979840u

static __device__ __forceinline__ unsigned short bfbits(float v) {
  bf16 b = (bf16)v;
  union { bf16 b; unsigned short u; } cvt; cvt.b = b; return cvt.u;
}

// ---------------------------------------------------------------------------
// Weight prep. ROUND-14: cases 0,1,2,4,7 now CHUNK-MAJOR [K/32][256][32]
// (zero-padded past K) so gemm_front can read B-fragments directly from
// global with 1KB-contiguous wave reads. Cases 8,9 stay flat for dualA.
// ---------------------------------------------------------------------------
__global__ __launch_bounds__(256) void wprep(
    const float* __restrict__ Wmu, const float* __restrict__ Wvar,
    const float* __restrict__ Wself, const float* __restrict__ Wother,
    const float* __restrict__ Wq, const float* __restrict__ Wk,
    const float* __restrict__ Wv, const float* __restrict__ Wa, char* wsb)
{
  const float* src; bf16* dst; int K, Kp; bool chunked = true;
  switch (blockIdx.y) {
    case 0: src = Wmu;        dst = (bf16*)(wsb + OFF_WT_MU);    K = 568; Kp = 576; break;
    case 1: src = Wvar;       dst = (bf16*)(wsb + OFF_WT_VAR);   K = 568; Kp = 576; break;
    case 2: src = Wself;      dst = (bf16*)(wsb + OFF_WT_SELF);  K = 36;  Kp = 64;  break;
    case 3: src = Wother;     dst = (bf16*)(wsb + OFF_WT_OTHER); K = 28;  Kp = 32;  break;
    case 4: src = Wq;         dst = (bf16*)(wsb + OFF_WT_Q);     K = 256; Kp = 256; break;
    case 5: src = Wk;         dst = (bf16*)(wsb + OFF_WT_K);     K = 256; Kp = 256; break;
    case 6: src = Wv;         dst = (bf16*)(wsb + OFF_WT_V1);    K = 256; Kp = 256; break;
    case 7: src = Wv + 65536; dst = (bf16*)(wsb + OFF_WT_V2);    K = 256; Kp = 256; break;
    case 8: src = Wa;         dst = (bf16*)(wsb + OFF_WT_A1);    K = 256; Kp = 256; chunked = false; break;
    default: src = Wa + 65536; dst = (bf16*)(wsb + OFF_WT_A2);   K = 256; Kp = 256; chunked = false; break;
  }
  int total = 256 * Kp;
  if (chunked) {
    for (int i = blockIdx.x * 256 + threadIdx.x; i < total; i += gridDim.x * 256) {
      int ch = i >> 13, n = (i >> 5) & 255, kk = i & 31;
      int k = ch * 32 + kk;
      dst[i] = (k < K) ? (bf16)src[k * 256 + n] : (bf16)0.f;
    }
  } else {
    for (int i = blockIdx.x * 256 + threadIdx.x; i < total; i += gridDim.x * 256) {
      int n = i / Kp, k = i - n * Kp;
      dst[i] = (k < K) ? (bf16)src[k * 256 + n] : (bf16)0.f;
    }
  }
}

// ---------------------------------------------------------------------------
// ROUND-14: fused front-end. Grid 512, 256 threads, BARRIER-FREE.
//   even blocks: z = eps*exp(0.5*(x@Wvar+b_var)) + x@Wmu+b_mu  (K=576, dual-B)
//                -> zl (wave-local LDS band, bf16)
//                -> q = relu(zl @ Wq + b_q)                    (K=256) -> global
//   odd blocks:  self = relu(x[:, :36] @ Wself + b_self)       (K=64)
//                -> global + zl
//                -> sv = zl @ Wv2 + b_v                        (K=256) -> global
// A-fragments read DIRECTLY from global (x as float4->bf16 cvt; zl from LDS);
// B-fragments read DIRECTLY from global chunk-major weights (1KB contiguous
// per wave-read, L2-resident). Each wave owns 16 rows end-to-end; zl is only
// ever touched by its owning wave -> no __syncthreads anywhere.
// Phase B ping-pongs B chunks; tail over-prefetch hits the adjacent
// allocated weight region (Wq ch8 -> WtK; Wv2 ch8 -> WtA1), discarded.
// ---------------------------------------------------------------------------
__global__ __launch_bounds__(256, 2) void gemm_front(
    const float* __restrict__ x,
    const bf16* __restrict__ WtMu, const bf16* __restrict__ WtVar,
    const bf16* __restrict__ WtSelf,
    const bf16* __restrict__ WtQc, const bf16* __restrict__ WtV2c,
    const float* __restrict__ b_mu, const float* __restrict__ b_var,
    const float* __restrict__ b_self,
    const float* __restrict__ b_q, const float* __restrict__ b_v,
    const float* __restrict__ eps,
    bf16* __restrict__ qout, bf16* __restrict__ selfout, bf16* __restrict__ svout)
{
  __shared__ bf16 zl[64 * 264];        // 33792 B; band [wave*16 .. wave*16+15] per wave

  const int tid = threadIdx.x;
  const int wave = tid >> 6;
  const int lane = tid & 63;
  const int quad = lane >> 4;
  const int m = lane & 15;
  const bool isZ = !(blockIdx.x & 1);
  const int rowbase = (blockIdx.x >> 1) * 64;

  const f32x4 z4 = {0.f, 0.f, 0.f, 0.f};
  f32x4 a1[16], a2[16];
#pragma unroll
  for (int ct = 0; ct < 16; ++ct) { a1[ct] = z4; a2[ct] = z4; }

  const int KA = isZ ? 576 : 64;
  const bf16* __restrict__ W1 = isZ ? WtMu : WtSelf;

  // ---- phase A: acc = x @ W1 (+ x @ Wvar), K = KA, no barriers
  for (int ch = 0; ch < KA / 32; ++ch) {
    const int kc = ch * 32;
    bf16x8 af;
    if (kc + quad * 8 < 568) {         // 568 % 8 == 0: all-or-nothing per quad
      const float* ap = x + (size_t)(rowbase + wave * 16 + m) * 568 + kc + quad * 8;
      float4 f0 = *(const float4*)ap;
      float4 f1 = *(const float4*)(ap + 4);
      af[0] = (bf16)f0.x; af[1] = (bf16)f0.y; af[2] = (bf16)f0.z; af[3] = (bf16)f0.w;
      af[4] = (bf16)f1.x; af[5] = (bf16)f1.y; af[6] = (bf16)f1.z; af[7] = (bf16)f1.w;
    } else {
#pragma unroll
      for (int e = 0; e < 8; ++e) af[e] = (bf16)0.f;
    }
    const bf16* bp1 = W1 + (size_t)ch * 8192 + m * 32 + quad * 8;
#pragma unroll
    for (int ct = 0; ct < 16; ++ct) {
      bf16x8 b1 = *(const bf16x8*)(bp1 + ct * 512);
      a1[ct] = __builtin_amdgcn_mfma_f32_16x16x32_bf16(af, b1, a1[ct], 0, 0, 0);
    }
    if (isZ) {
      const bf16* bp2 = WtVar + (size_t)ch * 8192 + m * 32 + quad * 8;
#pragma unroll
      for (int ct = 0; ct < 16; ++ct) {
        bf16x8 b2 = *(const bf16x8*)(bp2 + ct * 512);
        a2[ct] = __builtin_amdgcn_mfma_f32_16x16x32_bf16(af, b2, a2[ct], 0, 0, 0);
      }
    }
  }

  // ---- phase A epilogue: z (or self) -> bf16 -> zl (wave-local band)
#pragma unroll
  for (int ct = 0; ct < 16; ++ct) {
    const int col = ct * 16 + m;
    const float bv1 = isZ ? b_mu[col] : b_self[col];
    const float bv2 = isZ ? b_var[col] : 0.f;
#pragma unroll
    for (int r = 0; r < 4; ++r) {
      const int rowl = wave * 16 + quad * 4 + r;
      const size_t row = (size_t)rowbase + rowl;
      float v;
      if (isZ) {
        float mu = a1[ct][r] + bv1;
        float lv = a2[ct][r] + bv2;
        v = eps[row * 256 + col] * __expf(0.5f * lv) + mu;
      } else {
        v = a1[ct][r] + bv1;
        v = v > 0.f ? v : 0.f;
      }
      unsigned u = bfbits(v);
      unsigned other = (unsigned)__shfl_xor((int)u, 1, 64);
      if ((m & 1) == 0) {
        unsigned pk = u | (other << 16);
        *(unsigned*)(zl + rowl * 264 + col) = pk;
        if (!isZ) *(unsigned*)(selfout + row * 256 + col) = pk;
      }
    }
  }

  // ---- phase B: out = zl @ W3 (+bias, relu for q), K=256, ping-pong B
#pragma unroll
  for (int ct = 0; ct < 16; ++ct) a1[ct] = z4;
  const bf16* __restrict__ W3 = isZ ? WtQc : WtV2c;
  const int cb2 = m * 32 + quad * 8;
  bf16x8 pA[16], pB[16];
#pragma unroll
  for (int ct = 0; ct < 16; ++ct) pA[ct] = *(const bf16x8*)(W3 + cb2 + ct * 512);
#pragma unroll 1
  for (int ch2 = 0; ch2 < 8; ch2 += 2) {
#pragma unroll
    for (int ct = 0; ct < 16; ++ct)
      pB[ct] = *(const bf16x8*)(W3 + (size_t)(ch2 + 1) * 8192 + cb2 + ct * 512);
    bf16x8 af0 = *(const bf16x8*)(zl + (wave * 16 + m) * 264 + ch2 * 32 + quad * 8);
#pragma unroll
    for (int ct = 0; ct < 16; ++ct)
      a1[ct] = __builtin_amdgcn_mfma_f32_16x16x32_bf16(af0, pA[ct], a1[ct], 0, 0, 0);
    // prefetch ch2+2; ch2==6 reads chunk 8 = adjacent allocated region
#pragma unroll
    for (int ct = 0; ct < 16; ++ct)
      pA[ct] = *(const bf16x8*)(W3 + (size_t)(ch2 + 2) * 8192 + cb2 + ct * 512);
    bf16x8 af1 = *(const bf16x8*)(zl + (wave * 16 + m) * 264 + (ch2 + 1) * 32 + quad * 8);
#pragma unroll
    for (int ct = 0; ct < 16; ++ct)
      a1[ct] = __builtin_amdgcn_mfma_f32_16x16x32_bf16(af1, pB[ct], a1[ct], 0, 0, 0);
  }

  // ---- phase B epilogue -> global (q or sv)
  const float* __restrict__ b3 = isZ ? b_q : b_v;
  bf16* __restrict__ out3 = isZ ? qout : svout;
#pragma unroll
  for (int ct = 0; ct < 16; ++ct) {
    const int col = ct * 16 + m;
    const float bv = b3[col];
#pragma unroll
    for (int r = 0; r < 4; ++r) {
      const size_t row = (size_t)rowbase + wave * 16 + quad * 4 + r;
      float v = a1[ct][r] + bv;
      if (isZ) v = v > 0.f ? v : 0.f;
      unsigned u = bfbits(v);
      unsigned other = (unsigned)__shfl_xor((int)u, 1, 64);
      if ((m & 1) == 0)
        *(unsigned*)(out3 + row * 256 + col) = u | (other << 16);
    }
  }
}

// Dedicated dual-A GEMM (unchanged)
template<bool UNUSED>
__global__ __launch_bounds__(256, 2) void gemm_dualA(
    const bf16* __restrict__ A1, const bf16* __restrict__ A2,
    const bf16* __restrict__ Wt1, const bf16* __restrict__ Wt2,
    const float* __restrict__ bias, float* __restrict__ outp)
{
  __shared__ bf16 ldsA[64 * 40];
  __shared__ bf16 ldsB[128 * 40];

  const int tid = threadIdx.x;
  const int wave = tid >> 6;
  const int lane = tid & 63;
  const int quad = lane >> 4;
  const int m = lane & 15;
  const int rowbase = blockIdx.x * 64;
  const int colbase = blockIdx.y * 128;

  f32x4 acc[8];
  const f32x4 z4 = {0.f, 0.f, 0.f, 0.f};
#pragma unroll
  for (int ct = 0; ct < 8; ++ct) acc[ct] = z4;

  for (int pass = 0; pass < 2; ++pass) {
    const bf16* Ap = (pass == 0) ? A1 : A2;
    const bf16* Wp = (pass == 0) ? Wt1 : Wt2;
    for (int kc = 0; kc < 256; kc += 32) {
      __syncthreads();
      {
        int p = tid;
        int r = p >> 2, f = p & 3;
        *(bf16x8*)(ldsA + r * 40 + f * 8) =
            *(const bf16x8*)(Ap + (size_t)(rowbase + r) * 256 + kc + f * 8);
      }
#pragma unroll
      for (int it = 0; it < 2; ++it) {
        int p = tid + 256 * it;
        int n = p >> 2, f = p & 3;
        *(bf16x8*)(ldsB + n * 40 + f * 8) =
            *(const bf16x8*)(Wp + (size_t)(colbase + n) * 256 + kc + f * 8);
      }
      __syncthreads();
      bf16x8 afrag = *(const bf16x8*)(ldsA + (wave * 16 + m) * 40 + quad * 8);
#pragma unroll
      for (int ct = 0; ct < 8; ++ct) {
        bf16x8 bfrag = *(const bf16x8*)(ldsB + (ct * 16 + m) * 40 + quad * 8);
        acc[ct] = __builtin_amdgcn_mfma_f32_16x16x32_bf16(afrag, bfrag, acc[ct], 0, 0, 0);
      }
    }
  }
#pragma unroll
  for (int ct = 0; ct < 8; ++ct) {
    const int col = colbase + ct * 16 + m;
    const float bv = bias[col];
#pragma unroll
    for (int r = 0; r < 4; ++r) {
      const size_t row = (size_t)rowbase + wave * 16 + quad * 4 + r;
      float v = acc[ct][r] + bv;
      outp[row * 256 + col] = (v > 0.f ? v : 0.f);
    }
  }
}

// ---------------------------------------------------------------------------
// Fused attention (unchanged from round 13).
// ---------------------------------------------------------------------------
__global__ __launch_bounds__(512, 4) void k_fused(
    const float* __restrict__ x, const bf16* __restrict__ qb,
    const bf16* __restrict__ svb,
    const bf16* __restrict__ WtOther, const float* __restrict__ b_other,
    const bf16* __restrict__ WtKc, const float* __restrict__ b_k,
    const bf16* __restrict__ WtVc,
    float* __restrict__ att_out, bf16* __restrict__ hb)
{
  __shared__ bf16 ldsO[80 * 264];     // 42240 B  other_em (16B-group stride 33)
  __shared__ bf16 ldsA1[80 * 40];     //  6400 B  agents tile; REUSED: spart/attl
  __shared__ bf16 qh16[1024];         //  2048 B  q (bf16); REUSED: h partials
  __shared__ bf16 svl16[1024];        //  2048 B  sv (bf16)
  float* spart = (float*)ldsA1;        // [0..320)  floats: 4 K-waves x 80 rows
  float* attl  = (float*)ldsA1 + 320;  // [320..400) floats: att weights, row order

  const int tid = threadIdx.x, wave = tid >> 6, lane = tid & 63;
  const int quad = lane >> 4, m = lane & 15;
  const int b0 = blockIdx.x * 4;
  const int kvw = wave & 3;            // column-group within K or V half
  const bool isV = wave >= 4;

  // ---- phase 0: stage q, sv (bf16 copies), agents_info (interleaved rows)
  ((unsigned*)qh16)[tid]  = ((const unsigned*)(qb  + (size_t)b0 * 256))[tid];
  ((unsigned*)svl16)[tid] = ((const unsigned*)(svb + (size_t)b0 * 256))[tid];
  for (int i = tid; i < 80 * 16; i += 512) {
    int r = i >> 4, kk = (i & 15) * 2;   // lds row r = agent*4 + batch
    int n = r >> 2, bb = r & 3;
    float v0 = 0.f, v1 = 0.f;
    if (n < 19) {
      const float* base = x + (size_t)(b0 + bb) * NOBS + 36 + n * 28;
      if (kk < 28) v0 = base[kk];
      if (kk + 1 < 28) v1 = base[kk + 1];
    }
    unsigned u0 = bfbits(v0), u1 = bfbits(v1);
    *(unsigned*)(ldsA1 + r * 40 + kk) = u0 | (u1 << 16);
  }

  const f32x4 z4 = {0.f, 0.f, 0.f, 0.f};

  // ---- issue first main-loop B buffer early (independent of all LDS)
  const bf16* __restrict__ Bc = isV ? WtVc : WtKc;
  const int cb = (kvw * 64 + m) * 32 + quad * 8;   // ((4*kvw+c)*16+m)*32+q*8 == cb+c*512
  bf16x8 bE[4];
#pragma unroll
  for (int c = 0; c < 4; ++c) bE[c] = *(const bf16x8*)(Bc + cb + c * 512);

  __syncthreads();

  // ---- phase 1: other_em = relu(A1 @ WtOther^T + b_other), K=32.
  // 8 waves x 2 col-tiles each = 256 cols.
  {
    float bo[2];
    bf16x8 bfr[2];
#pragma unroll
    for (int c = 0; c < 2; ++c) {
      int col = (2 * wave + c) * 16 + m;
      bo[c] = b_other[col];
      bfr[c] = *(const bf16x8*)(WtOther + col * 32 + quad * 8);
    }
    f32x4 acc1[5][2];
#pragma unroll
    for (int rt = 0; rt < 5; ++rt) {
      bf16x8 a = *(const bf16x8*)(ldsA1 + (rt * 16 + m) * 40 + quad * 8);
#pragma unroll
      for (int c = 0; c < 2; ++c)
        acc1[rt][c] = __builtin_amdgcn_mfma_f32_16x16x32_bf16(a, bfr[c], z4, 0, 0, 0);
    }
#pragma unroll
    for (int rt = 0; rt < 5; ++rt)
#pragma unroll
      for (int c = 0; c < 2; ++c) {
        int col = (2 * wave + c) * 16 + m;
#pragma unroll
        for (int r = 0; r < 4; ++r) {
          float v = acc1[rt][c][r] + bo[c];
          v = v > 0.f ? v : 0.f;
          unsigned u = bfbits(v);
          unsigned other = (unsigned)__shfl_xor((int)u, 1, 64);
          if ((m & 1) == 0) {
            int rowl = rt * 16 + quad * 4 + r;
            *(unsigned*)(ldsO + rowl * 264 + col) = u | (other << 16);
          }
        }
      }
  }
  __syncthreads();   // ldsA1 (agents tile) dead from here; spart/attl overlay

  // ---- unified main GEMM: 80 rows x 512 cols ([WtK | WtV]), 8 chunks,
  // ping-pong software pipeline (prefetch distance 1, no conditionals).
  f32x4 acc[5][4];
#pragma unroll
  for (int rt = 0; rt < 5; ++rt)
#pragma unroll
    for (int c = 0; c < 4; ++c) acc[rt][c] = z4;

  {
#pragma unroll 1
    for (int ch = 0; ch < 8; ch += 2) {
      bf16x8 bO[4];
#pragma unroll
      for (int c = 0; c < 4; ++c)
        bO[c] = *(const bf16x8*)(Bc + (size_t)(ch + 1) * 8192 + cb + c * 512);
      const int kc0 = ch * 32;
#pragma unroll
      for (int rt = 0; rt < 5; ++rt) {
        bf16x8 a = *(const bf16x8*)(ldsO + (rt * 16 + m) * 264 + kc0 + quad * 8);
#pragma unroll
        for (int c = 0; c < 4; ++c)
          acc[rt][c] = __builtin_amdgcn_mfma_f32_16x16x32_bf16(a, bE[c], acc[rt][c], 0, 0, 0);
      }
      // prefetch ch+2; at ch==6 this reads chunk 8 = adjacent weight region
      // (allocated, discarded) -- avoids any tail conditional.
#pragma unroll
      for (int c = 0; c < 4; ++c)
        bE[c] = *(const bf16x8*)(Bc + (size_t)(ch + 2) * 8192 + cb + c * 512);
      const int kc1 = kc0 + 32;
#pragma unroll
      for (int rt = 0; rt < 5; ++rt) {
        bf16x8 a = *(const bf16x8*)(ldsO + (rt * 16 + m) * 264 + kc1 + quad * 8);
#pragma unroll
        for (int c = 0; c < 4; ++c)
          acc[rt][c] = __builtin_amdgcn_mfma_f32_16x16x32_bf16(a, bO[c], acc[rt][c], 0, 0, 0);
      }
    }
  }

  // ---- K-waves: scores = (relu(k)+b_k) . q, reduce over lanes -> spart
  if (!isV) {
    float qreg[4][4], bkreg[4];
#pragma unroll
    for (int c = 0; c < 4; ++c) {
      int col = (4 * wave + c) * 16 + m;
      bkreg[c] = b_k[col];
#pragma unroll
      for (int r = 0; r < 4; ++r) qreg[c][r] = (float)qh16[r * 256 + col];
    }
#pragma unroll
    for (int rt = 0; rt < 5; ++rt) {
      float part[4] = {0.f, 0.f, 0.f, 0.f};
#pragma unroll
      for (int c = 0; c < 4; ++c) {
#pragma unroll
        for (int r = 0; r < 4; ++r) {
          float kv = acc[rt][c][r] + bkreg[c];
          kv = kv > 0.f ? kv : 0.f;
          part[r] += kv * qreg[c][r];
        }
      }
#pragma unroll
      for (int r = 0; r < 4; ++r) {
        float p = part[r];
        p += __shfl_xor(p, 1, 64);
        p += __shfl_xor(p, 2, 64);
        p += __shfl_xor(p, 4, 64);
        p += __shfl_xor(p, 8, 64);
        if (m == 0) spart[wave * 80 + rt * 16 + quad * 4 + r] = p;
      }
    }
  }
  __syncthreads();

  // ---- softmax: wave w = batch w, lanes 0-18 = agents (width-32 tree)
  if (!isV && lane < 32) {
    const int bb = wave, j = lane;      // batch, agent
    float s = -1e30f;
    if (j < 19) {
      int row = j * 4 + bb;             // interleaved: row = agent*4 + batch
      s = (spart[row] + spart[80 + row] + spart[160 + row] + spart[240 + row]) * 0.0625f;
    }
    float mx = s;
#pragma unroll
    for (int off = 16; off >= 1; off >>= 1) mx = fmaxf(mx, __shfl_xor(mx, off, 32));
    float e = (j < 19) ? __expf(s - mx) : 0.f;
    float sum = e;
#pragma unroll
    for (int off = 16; off >= 1; off >>= 1) sum += __shfl_xor(sum, off, 32);
    float inv = 1.f / sum;
    float a = e * inv;
    if (j < 20) attl[j * 4 + bb] = a;   // j==19 writes the zero pad row
    if (j < 19) att_out[(size_t)(b0 + bb) * 19 + j] = a;
  }
  __syncthreads();

  // ---- V-waves: epilogue  h = sum_rows att * relu(v + sv)
  if (isV) {
    float svreg[4][4];
#pragma unroll
    for (int c = 0; c < 4; ++c) {
      int col = (4 * kvw + c) * 16 + m;
#pragma unroll
      for (int r = 0; r < 4; ++r) svreg[c][r] = (float)svl16[r * 256 + col];
    }
    float hacc[4][4];   // [c][batch==r]
#pragma unroll
    for (int c = 0; c < 4; ++c)
#pragma unroll
      for (int r = 0; r < 4; ++r) hacc[c][r] = 0.f;
#pragma unroll
    for (int rt = 0; rt < 5; ++rt) {
      float av[4];
#pragma unroll
      for (int r = 0; r < 4; ++r) av[r] = attl[rt * 16 + quad * 4 + r];
#pragma unroll
      for (int c = 0; c < 4; ++c) {
#pragma unroll
        for (int r = 0; r < 4; ++r) {
          float v = acc[rt][c][r] + svreg[c][r];
          v = v > 0.f ? v : 0.f;
          hacc[c][r] += v * av[r];
        }
      }
    }
    // reduce over quads (rows); K-waves' qh16 reads all precede barrier 1.
#pragma unroll
    for (int c = 0; c < 4; ++c)
#pragma unroll
      for (int r = 0; r < 4; ++r) {
        float h = hacc[c][r];
        h += __shfl_xor(h, 16, 64);
        h += __shfl_xor(h, 32, 64);
        if (quad == 0) qh16[r * 256 + (4 * kvw + c) * 16 + m] = (bf16)h;
      }
  }
  __syncthreads();
  ((unsigned*)(hb + (size_t)b0 * 256))[tid] = ((const unsigned*)qh16)[tid];
}

// ---------------------------------------------------------------------------
extern "C" void kernel_launch(void* const* d_in, const int* in_sizes, int n_in,
                              void* d_out, int out_size, void* d_ws, size_t ws_size,
                              hipStream_t stream) {
  (void)in_sizes; (void)n_in; (void)out_size; (void)ws_size;
  const float* x      = (const float*)d_in[0];
  const float* eps    = (const float*)d_in[1];
  const float* W_mu   = (const float*)d_in[2];
  const float* b_mu   = (const float*)d_in[3];
  const float* W_var  = (const float*)d_in[4];
  const float* b_var  = (const float*)d_in[5];
  const float* W_self = (const float*)d_in[6];
  const float* b_self = (const float*)d_in[7];
  const float* W_other= (const float*)d_in[8];
  const float* b_other= (const float*)d_in[9];
  const float* W_q    = (const float*)d_in[10];
  const float* b_q    = (const float*)d_in[11];
  const float* W_k    = (const float*)d_in[12];
  const float* b_k    = (const float*)d_in[13];
  const float* W_v    = (const float*)d_in[14];
  const float* b_v    = (const float*)d_in[15];
  const float* W_a    = (const float*)d_in[16];
  const float* b_a    = (const float*)d_in[17];

  char* wsb = (char*)d_ws;
  bf16* WtMu    = (bf16*)(wsb + OFF_WT_MU);
  bf16* WtVar   = (bf16*)(wsb + OFF_WT_VAR);
  bf16* WtSelf  = (bf16*)(wsb + OFF_WT_SELF);
  bf16* WtOther = (bf16*)(wsb + OFF_WT_OTHER);
  bf16* WtQ     = (bf16*)(wsb + OFF_WT_Q);
  bf16* WtK     = (bf16*)(wsb + OFF_WT_K);
  bf16* WtV1    = (bf16*)(wsb + OFF_WT_V1);
  bf16* WtV2    = (bf16*)(wsb + OFF_WT_V2);
  bf16* WtA1    = (bf16*)(wsb + OFF_WT_A1);
  bf16* WtA2    = (bf16*)(wsb + OFF_WT_A2);
  bf16* selfbuf = (bf16*)(wsb + OFF_SELF);
  bf16* qbuf    = (bf16*)(wsb + OFF_Q);
  bf16* svbuf   = (bf16*)(wsb + OFF_SV);
  bf16* hbuf    = (bf16*)(wsb + OFF_H);

  float* out = (float*)d_out;
  float* att_out = out + (size_t)NB * 256;

  dim3 blk(256);
  wprep<<<dim3(160, 10), blk, 0, stream>>>(W_mu, W_var, W_self, W_other, W_q, W_k, W_v, W_a, wsb);
  // fused front-end: {z->q} (even blocks) and {self->sv} (odd blocks)
  gemm_front<<<512, blk, 0, stream>>>(x, WtMu, WtVar, WtSelf, WtQ, WtV2,
                                      b_mu, b_var, b_self, b_q, b_v, eps,
                                      qbuf, selfbuf, svbuf);
  // fused: other_em -> [k | v] unified GEMM -> scores -> softmax -> h
  k_fused<<<NB / 4, dim3(512), 0, stream>>>(x, qbuf, svbuf, WtOther, b_other, WtK, b_k,
                                            WtV1, att_out, hbuf);
  // out = relu([h; self_em] @ W_a + b_a)   (dedicated dual-A kernel)
  gemm_dualA<true><<<dim3(NB / 64, 2), blk, 0, stream>>>(hbuf, selfbuf, WtA1, WtA2, b_a, out);
}

// Round 5
// 336.566 us; speedup vs baseline: 1.1526x; 1.1526x over previous
//
#include <hip/hip_runtime.h>

typedef __bf16 bf16;
typedef __bf16 bf16x4 __attribute__((ext_vector_type(4)));
typedef __bf16 bf16x8 __attribute__((ext_vector_type(8)));
typedef float  f32x4  __attribute__((ext_vector_type(4)));

// Problem constants
#define NB    16384      // batch
#define NOBS  568
#define NH    256
#define NAG   19         // N_OTHER

// ws byte offsets (all 16B aligned)
#define OFF_WT_MU    0u          // FLAT [256][576] bf16 (zself stages via LDS)
#define OFF_WT_VAR   294912u     // FLAT [256][576]
#define OFF_WT_SELF  589824u     // FLAT [256][64]
#define OFF_WT_OTHER 622592u     // [256][32]  (chunk-major == flat at K=32)
#define OFF_WT_Q     638976u     // CHUNK-MAJOR [8][256][32]
#define OFF_WT_K     770048u     // CHUNK-MAJOR [8][256][32]  (K chunk-8 overflow -> V1)
#define OFF_WT_V1    901120u     // CHUNK-MAJOR [8][256][32]  (V1 chunk-8 overflow -> V2)
#define OFF_WT_V2    1032192u    // CHUNK-MAJOR [8][256][32]
#define OFF_WT_A1    1163264u    // CHUNK-MAJOR [8][256][32]
#define OFF_WT_A2    1294336u    // CHUNK-MAJOR [8][256][32]
#define OFF_Z        1425408u    // [16384][256] bf16
#define OFF_SELF     9814016u
#define OFF_Q        18202624u
#define OFF_SV       26591232u   // bf16 (includes b_v)
#define OFF_H        34979840u

static __device__ __forceinline__ unsigned short bfbits(float v) {
  bf16 b = (bf16)v;
  union { bf16 b; unsigned short u; } cvt; cvt.b = b; return cvt.u;
}

// async global->LDS, 16B per lane; dest = wave-uniform base + lane*16
static __device__ __forceinline__ void gload16(const bf16* g, bf16* l) {
  __builtin_amdgcn_global_load_lds(
      (const __attribute__((address_space(1))) void*)g,
      (__attribute__((address_space(3))) void*)(void*)l, 16, 0, 0);
}

// ---------------------------------------------------------------------------
// Weight prep. ROUND-15: cases 4,7,8,9 chunk-major [8][256][32] for the
// async-staged GEMMs (contiguous 4KB B-stage reads); 0,1,2 flat for zself;
// 5,6 chunk-major for k_fused (as always).
// ---------------------------------------------------------------------------
__global__ __launch_bounds__(256) void wprep(
    const float* __restrict__ Wmu, const float* __restrict__ Wvar,
    const float* __restrict__ Wself, const float* __restrict__ Wother,
    const float* __restrict__ Wq, const float* __restrict__ Wk,
    const float* __restrict__ Wv, const float* __restrict__ Wa, char* wsb)
{
  const float* src; bf16* dst; int K, Kp; bool chunked = false;
  switch (blockIdx.y) {
    case 0: src = Wmu;        dst = (bf16*)(wsb + OFF_WT_MU);    K = 568; Kp = 576; break;
    case 1: src = Wvar;       dst = (bf16*)(wsb + OFF_WT_VAR);   K = 568; Kp = 576; break;
    case 2: src = Wself;      dst = (bf16*)(wsb + OFF_WT_SELF);  K = 36;  Kp = 64;  break;
    case 3: src = Wother;     dst = (bf16*)(wsb + OFF_WT_OTHER); K = 28;  Kp = 32;  break;
    case 4: src = Wq;         dst = (bf16*)(wsb + OFF_WT_Q);     K = 256; Kp = 256; chunked = true; break;
    case 5: src = Wk;         dst = (bf16*)(wsb + OFF_WT_K);     K = 256; Kp = 256; chunked = true; break;
    case 6: src = Wv;         dst = (bf16*)(wsb + OFF_WT_V1);    K = 256; Kp = 256; chunked = true; break;
    case 7: src = Wv + 65536; dst = (bf16*)(wsb + OFF_WT_V2);    K = 256; Kp = 256; chunked = true; break;
    case 8: src = Wa;         dst = (bf16*)(wsb + OFF_WT_A1);    K = 256; Kp = 256; chunked = true; break;
    default: src = Wa + 65536; dst = (bf16*)(wsb + OFF_WT_A2);   K = 256; Kp = 256; chunked = true; break;
  }
  int total = 256 * Kp;
  if (chunked) {
    for (int i = blockIdx.x * 256 + threadIdx.x; i < total; i += gridDim.x * 256) {
      int ch = i >> 13, n = (i >> 5) & 255, kk = i & 31;
      int k = ch * 32 + kk;
      dst[i] = (bf16)src[k * 256 + n];
    }
  } else {
    for (int i = blockIdx.x * 256 + threadIdx.x; i < total; i += gridDim.x * 256) {
      int n = i / Kp, k = i - n * Kp;
      dst[i] = (k < K) ? (bf16)src[k * 256 + n] : (bf16)0.f;
    }
  }
}

// ---------------------------------------------------------------------------
// Merged z + self GEMM (exact round-3 version).
// ---------------------------------------------------------------------------
__global__ __launch_bounds__(256, 3) void gemm_zself(
    const float* __restrict__ x,
    const bf16* __restrict__ WtMu, const bf16* __restrict__ WtVar,
    const bf16* __restrict__ WtSelf,
    const float* __restrict__ b_mu, const float* __restrict__ b_var,
    const float* __restrict__ b_self, const float* __restrict__ eps,
    bf16* __restrict__ zout, bf16* __restrict__ selfout)
{
  __shared__ bf16 ldsA[64 * 40];
  __shared__ bf16 ldsB[128 * 40];
  __shared__ bf16 ldsB2[128 * 40];

  const int tid = threadIdx.x;
  const int wave = tid >> 6;
  const int lane = tid & 63;
  const int quad = lane >> 4;
  const int m = lane & 15;
  const int rowbase = blockIdx.x * 64;
  const int colbase = (blockIdx.y & 1) * 128;
  const bool isZ = blockIdx.y < 2;
  const int K = isZ ? 576 : 64;
  const bf16* __restrict__ Wt = isZ ? WtMu : WtSelf;
  const float* __restrict__ bias = isZ ? b_mu : b_self;

  f32x4 acc[8], accB[8];
  const f32x4 z4 = {0.f, 0.f, 0.f, 0.f};
#pragma unroll
  for (int ct = 0; ct < 8; ++ct) { acc[ct] = z4; accB[ct] = z4; }

  for (int kc = 0; kc < K; kc += 32) {
    __syncthreads();
    {
#pragma unroll
      for (int it = 0; it < 2; ++it) {
        int p = tid + 256 * it;          // 512 float4 segments (64 rows x 8)
        int r = p >> 3, fs = p & 7;
        int k = kc + fs * 4;
        const float* src = x + (size_t)(rowbase + r) * 568 + k;
        float v0, v1, v2, v3;
        if (k + 4 <= 568) {
          float4 v = *(const float4*)src;
          v0 = v.x; v1 = v.y; v2 = v.z; v3 = v.w;
        } else {
          v0 = (k + 0 < 568) ? src[0] : 0.f;
          v1 = (k + 1 < 568) ? src[1] : 0.f;
          v2 = (k + 2 < 568) ? src[2] : 0.f;
          v3 = (k + 3 < 568) ? src[3] : 0.f;
        }
        bf16x4 o = {(bf16)v0, (bf16)v1, (bf16)v2, (bf16)v3};
        *(bf16x4*)(ldsA + r * 40 + fs * 4) = o;
      }
    }
#pragma unroll
    for (int it = 0; it < 2; ++it) {
      int p = tid + 256 * it;             // 512 bf16x8 segments (128 rows x 4)
      int n = p >> 2, f = p & 3;
      *(bf16x8*)(ldsB + n * 40 + f * 8) =
          *(const bf16x8*)(Wt + (size_t)(colbase + n) * K + kc + f * 8);
    }
    if (isZ) {
#pragma unroll
      for (int it = 0; it < 2; ++it) {
        int p = tid + 256 * it;
        int n = p >> 2, f = p & 3;
        *(bf16x8*)(ldsB2 + n * 40 + f * 8) =
            *(const bf16x8*)(WtVar + (size_t)(colbase + n) * 576 + kc + f * 8);
      }
    }
    __syncthreads();
    bf16x8 afrag = *(const bf16x8*)(ldsA + (wave * 16 + m) * 40 + quad * 8);
#pragma unroll
    for (int ct = 0; ct < 8; ++ct) {
      bf16x8 bfrag = *(const bf16x8*)(ldsB + (ct * 16 + m) * 40 + quad * 8);
      acc[ct] = __builtin_amdgcn_mfma_f32_16x16x32_bf16(afrag, bfrag, acc[ct], 0, 0, 0);
      if (isZ) {
        bf16x8 b2 = *(const bf16x8*)(ldsB2 + (ct * 16 + m) * 40 + quad * 8);
        accB[ct] = __builtin_amdgcn_mfma_f32_16x16x32_bf16(afrag, b2, accB[ct], 0, 0, 0);
      }
    }
  }
#pragma unroll
  for (int ct = 0; ct < 8; ++ct) {
    const int col = colbase + ct * 16 + m;
    const float bv = bias[col];
#pragma unroll
    for (int r = 0; r < 4; ++r) {
      const size_t row = (size_t)rowbase + wave * 16 + quad * 4 + r;
      float v = acc[ct][r] + bv;
      if (isZ) {
        float lv = accB[ct][r] + b_var[col];
        float zz = eps[row * 256 + col] * __expf(0.5f * lv) + v;
        zout[row * 256 + col] = (bf16)zz;
      } else {
        selfout[row * 256 + col] = (bf16)(v > 0.f ? v : 0.f);
      }
    }
  }
}

// ---------------------------------------------------------------------------
// ROUND-15: q + sv GEMM with global_load_lds + 2-phase async double-buffer.
// Linear LDS tiles ([64][32] A, [128][32] B, no pad -- required by
// global_load_lds linear dest). One barrier per K-step; stage(next) issues
// before compute(cur). LDS 24KB -> 6 blocks/CU (was 2).
// ---------------------------------------------------------------------------
__global__ __launch_bounds__(256, 4) void gemm_qsv(
    const bf16* __restrict__ zb, const bf16* __restrict__ selfb,
    const bf16* __restrict__ WtQc, const bf16* __restrict__ WtV2c,
    const float* __restrict__ b_q, const float* __restrict__ b_v,
    bf16* __restrict__ qout, bf16* __restrict__ svout)
{
  __shared__ __align__(16) bf16 lA[2][64 * 32];
  __shared__ __align__(16) bf16 lB[2][128 * 32];

  const int tid = threadIdx.x;
  const int wave = tid >> 6;
  const int lane = tid & 63;
  const int quad = lane >> 4;
  const int m = lane & 15;
  const int rowbase = blockIdx.x * 64;
  const int colbase = (blockIdx.y & 1) * 128;
  const bool isQ = blockIdx.y < 2;
  const bf16* __restrict__ Ap = isQ ? zb : selfb;
  const bf16* __restrict__ Wc = isQ ? WtQc : WtV2c;
  const float* __restrict__ bias = isQ ? b_q : b_v;
  bf16* __restrict__ outp = isQ ? qout : svout;

  f32x4 acc[8];
  const f32x4 z4 = {0.f, 0.f, 0.f, 0.f};
#pragma unroll
  for (int ct = 0; ct < 8; ++ct) acc[ct] = z4;

  const size_t arow = (size_t)(rowbase + (tid >> 2)) * 256 + (tid & 3) * 8;
  const size_t bbase = (size_t)colbase * 32 + (size_t)tid * 8;

  // prologue: stage chunk 0 into buffer 0
  gload16(Ap + arow, &lA[0][wave * 512]);
  gload16(Wc + bbase, &lB[0][wave * 512]);
  gload16(Wc + bbase + 2048, &lB[0][2048 + wave * 512]);
  __syncthreads();

#pragma unroll
  for (int ch = 0; ch < 8; ++ch) {
    const int cur = ch & 1;
    if (ch < 7) {
      const int nxt = cur ^ 1;
      const size_t cof = (size_t)(ch + 1) * 8192;
      gload16(Ap + arow + (ch + 1) * 32, &lA[nxt][wave * 512]);
      gload16(Wc + cof + bbase, &lB[nxt][wave * 512]);
      gload16(Wc + cof + bbase + 2048, &lB[nxt][2048 + wave * 512]);
    }
    bf16x8 afrag = *(const bf16x8*)(&lA[cur][(wave * 16 + m) * 32 + quad * 8]);
#pragma unroll
    for (int ct = 0; ct < 8; ++ct) {
      bf16x8 bfrag = *(const bf16x8*)(&lB[cur][(ct * 16 + m) * 32 + quad * 8]);
      acc[ct] = __builtin_amdgcn_mfma_f32_16x16x32_bf16(afrag, bfrag, acc[ct], 0, 0, 0);
    }
    __syncthreads();
  }

#pragma unroll
  for (int ct = 0; ct < 8; ++ct) {
    const int col = colbase + ct * 16 + m;
    const float bv = bias[col];
#pragma unroll
    for (int r = 0; r < 4; ++r) {
      const size_t row = (size_t)rowbase + wave * 16 + quad * 4 + r;
      float v = acc[ct][r] + bv;
      if (isQ) v = (v > 0.f ? v : 0.f);
      outp[row * 256 + col] = (bf16)v;
    }
  }
}

// ---------------------------------------------------------------------------
// ROUND-15: dual-A GEMM (out = relu([h; self]@Wa+b)) with global_load_lds +
// 2-phase async double-buffer; 16 unified K-steps across the two passes.
// ---------------------------------------------------------------------------
__global__ __launch_bounds__(256, 4) void gemm_dualA(
    const bf16* __restrict__ A1, const bf16* __restrict__ A2,
    const bf16* __restrict__ Wt1c, const bf16* __restrict__ Wt2c,
    const float* __restrict__ bias, float* __restrict__ outp)
{
  __shared__ __align__(16) bf16 lA[2][64 * 32];
  __shared__ __align__(16) bf16 lB[2][128 * 32];

  const int tid = threadIdx.x;
  const int wave = tid >> 6;
  const int lane = tid & 63;
  const int quad = lane >> 4;
  const int m = lane & 15;
  const int rowbase = blockIdx.x * 64;
  const int colbase = blockIdx.y * 128;

  f32x4 acc[8];
  const f32x4 z4 = {0.f, 0.f, 0.f, 0.f};
#pragma unroll
  for (int ct = 0; ct < 8; ++ct) acc[ct] = z4;

  const size_t arow = (size_t)(rowbase + (tid >> 2)) * 256 + (tid & 3) * 8;
  const size_t bbase = (size_t)colbase * 32 + (size_t)tid * 8;

  // stage step t (t = pass*8 + ch) into buffer buf
  auto stageT = [&](int buf, int t) {
    const int ch = t & 7;
    const bf16* Astep = (t < 8) ? A1 : A2;
    const bf16* Wstep = (t < 8) ? Wt1c : Wt2c;
    const size_t cof = (size_t)ch * 8192;
    gload16(Astep + arow + ch * 32, &lA[buf][wave * 512]);
    gload16(Wstep + cof + bbase, &lB[buf][wave * 512]);
    gload16(Wstep + cof + bbase + 2048, &lB[buf][2048 + wave * 512]);
  };

  stageT(0, 0);
  __syncthreads();

#pragma unroll
  for (int t = 0; t < 16; ++t) {
    const int cur = t & 1;
    if (t < 15) stageT(cur ^ 1, t + 1);
    bf16x8 afrag = *(const bf16x8*)(&lA[cur][(wave * 16 + m) * 32 + quad * 8]);
#pragma unroll
    for (int ct = 0; ct < 8; ++ct) {
      bf16x8 bfrag = *(const bf16x8*)(&lB[cur][(ct * 16 + m) * 32 + quad * 8]);
      acc[ct] = __builtin_amdgcn_mfma_f32_16x16x32_bf16(afrag, bfrag, acc[ct], 0, 0, 0);
    }
    __syncthreads();
  }

#pragma unroll
  for (int ct = 0; ct < 8; ++ct) {
    const int col = colbase + ct * 16 + m;
    const float bv = bias[col];
#pragma unroll
    for (int r = 0; r < 4; ++r) {
      const size_t row = (size_t)rowbase + wave * 16 + quad * 4 + r;
      float v = acc[ct][r] + bv;
      outp[row * 256 + col] = (v > 0.f ? v : 0.f);
    }
  }
}

// ---------------------------------------------------------------------------
// Fused attention (exact round-3/13 version; best measured 159 us).
// ---------------------------------------------------------------------------
__global__ __launch_bounds__(512, 4) void k_fused(
    const float* __restrict__ x, const bf16* __restrict__ qb,
    const bf16* __restrict__ svb,
    const bf16* __restrict__ WtOther, const float* __restrict__ b_other,
    const bf16* __restrict__ WtKc, const float* __restrict__ b_k,
    const bf16* __restrict__ WtVc,
    float* __restrict__ att_out, bf16* __restrict__ hb)
{
  __shared__ bf16 ldsO[80 * 264];     // 42240 B  other_em (16B-group stride 33)
  __shared__ bf16 ldsA1[80 * 40];     //  6400 B  agents tile; REUSED: spart/attl
  __shared__ bf16 qh16[1024];         //  2048 B  q (bf16); REUSED: h partials
  __shared__ bf16 svl16[1024];        //  2048 B  sv (bf16)
  float* spart = (float*)ldsA1;        // [0..320)  floats: 4 K-waves x 80 rows
  float* attl  = (float*)ldsA1 + 320;  // [320..400) floats: att weights, row order

  const int tid = threadIdx.x, wave = tid >> 6, lane = tid & 63;
  const int quad = lane >> 4, m = lane & 15;
  const int b0 = blockIdx.x * 4;
  const int kvw = wave & 3;            // column-group within K or V half
  const bool isV = wave >= 4;

  // ---- phase 0: stage q, sv (bf16 copies), agents_info (interleaved rows)
  ((unsigned*)qh16)[tid]  = ((const unsigned*)(qb  + (size_t)b0 * 256))[tid];
  ((unsigned*)svl16)[tid] = ((const unsigned*)(svb + (size_t)b0 * 256))[tid];
  for (int i = tid; i < 80 * 16; i += 512) {
    int r = i >> 4, kk = (i & 15) * 2;   // lds row r = agent*4 + batch
    int n = r >> 2, bb = r & 3;
    float v0 = 0.f, v1 = 0.f;
    if (n < 19) {
      const float* base = x + (size_t)(b0 + bb) * NOBS + 36 + n * 28;
      if (kk < 28) v0 = base[kk];
      if (kk + 1 < 28) v1 = base[kk + 1];
    }
    unsigned u0 = bfbits(v0), u1 = bfbits(v1);
    *(unsigned*)(ldsA1 + r * 40 + kk) = u0 | (u1 << 16);
  }

  const f32x4 z4 = {0.f, 0.f, 0.f, 0.f};

  // ---- issue first main-loop B buffer early (independent of all LDS)
  const bf16* __restrict__ Bc = isV ? WtVc : WtKc;
  const int cb = (kvw * 64 + m) * 32 + quad * 8;   // ((4*kvw+c)*16+m)*32+q*8 == cb+c*512
  bf16x8 bE[4];
#pragma unroll
  for (int c = 0; c < 4; ++c) bE[c] = *(const bf16x8*)(Bc + cb + c * 512);

  __syncthreads();

  // ---- phase 1: other_em = relu(A1 @ WtOther^T + b_other), K=32.
  {
    float bo[2];
    bf16x8 bfr[2];
#pragma unroll
    for (int c = 0; c < 2; ++c) {
      int col = (2 * wave + c) * 16 + m;
      bo[c] = b_other[col];
      bfr[c] = *(const bf16x8*)(WtOther + col * 32 + quad * 8);
    }
    f32x4 acc1[5][2];
#pragma unroll
    for (int rt = 0; rt < 5; ++rt) {
      bf16x8 a = *(const bf16x8*)(ldsA1 + (rt * 16 + m) * 40 + quad * 8);
#pragma unroll
      for (int c = 0; c < 2; ++c)
        acc1[rt][c] = __builtin_amdgcn_mfma_f32_16x16x32_bf16(a, bfr[c], z4, 0, 0, 0);
    }
#pragma unroll
    for (int rt = 0; rt < 5; ++rt)
#pragma unroll
      for (int c = 0; c < 2; ++c) {
        int col = (2 * wave + c) * 16 + m;
#pragma unroll
        for (int r = 0; r < 4; ++r) {
          float v = acc1[rt][c][r] + bo[c];
          v = v > 0.f ? v : 0.f;
          unsigned u = bfbits(v);
          unsigned other = (unsigned)__shfl_xor((int)u, 1, 64);
          if ((m & 1) == 0) {
            int rowl = rt * 16 + quad * 4 + r;
            *(unsigned*)(ldsO + rowl * 264 + col) = u | (other << 16);
          }
        }
      }
  }
  __syncthreads();   // ldsA1 (agents tile) dead from here; spart/attl overlay

  // ---- unified main GEMM: 80 rows x 512 cols ([WtK | WtV]), 8 chunks,
  // ping-pong software pipeline (prefetch distance 1, no conditionals).
  f32x4 acc[5][4];
#pragma unroll
  for (int rt = 0; rt < 5; ++rt)
#pragma unroll
    for (int c = 0; c < 4; ++c) acc[rt][c] = z4;

  {
#pragma unroll 1
    for (int ch = 0; ch < 8; ch += 2) {
      bf16x8 bO[4];
#pragma unroll
      for (int c = 0; c < 4; ++c)
        bO[c] = *(const bf16x8*)(Bc + (size_t)(ch + 1) * 8192 + cb + c * 512);
      const int kc0 = ch * 32;
#pragma unroll
      for (int rt = 0; rt < 5; ++rt) {
        bf16x8 a = *(const bf16x8*)(ldsO + (rt * 16 + m) * 264 + kc0 + quad * 8);
#pragma unroll
        for (int c = 0; c < 4; ++c)
          acc[rt][c] = __builtin_amdgcn_mfma_f32_16x16x32_bf16(a, bE[c], acc[rt][c], 0, 0, 0);
      }
      // prefetch ch+2; at ch==6 this reads chunk 8 = adjacent weight region
#pragma unroll
      for (int c = 0; c < 4; ++c)
        bE[c] = *(const bf16x8*)(Bc + (size_t)(ch + 2) * 8192 + cb + c * 512);
      const int kc1 = kc0 + 32;
#pragma unroll
      for (int rt = 0; rt < 5; ++rt) {
        bf16x8 a = *(const bf16x8*)(ldsO + (rt * 16 + m) * 264 + kc1 + quad * 8);
#pragma unroll
        for (int c = 0; c < 4; ++c)
          acc[rt][c] = __builtin_amdgcn_mfma_f32_16x16x32_bf16(a, bO[c], acc[rt][c], 0, 0, 0);
      }
    }
  }

  // ---- K-waves: scores = (relu(k)+b_k) . q, reduce over lanes -> spart
  if (!isV) {
    float qreg[4][4], bkreg[4];
#pragma unroll
    for (int c = 0; c < 4; ++c) {
      int col = (4 * wave + c) * 16 + m;
      bkreg[c] = b_k[col];
#pragma unroll
      for (int r = 0; r < 4; ++r) qreg[c][r] = (float)qh16[r * 256 + col];
    }
#pragma unroll
    for (int rt = 0; rt < 5; ++rt) {
      float part[4] = {0.f, 0.f, 0.f, 0.f};
#pragma unroll
      for (int c = 0; c < 4; ++c) {
#pragma unroll
        for (int r = 0; r < 4; ++r) {
          float kv = acc[rt][c][r] + bkreg[c];
          kv = kv > 0.f ? kv : 0.f;
          part[r] += kv * qreg[c][r];
        }
      }
#pragma unroll
      for (int r = 0; r < 4; ++r) {
        float p = part[r];
        p += __shfl_xor(p, 1, 64);
        p += __shfl_xor(p, 2, 64);
        p += __shfl_xor(p, 4, 64);
        p += __shfl_xor(p, 8, 64);
        if (m == 0) spart[wave * 80 + rt * 16 + quad * 4 + r] = p;
      }
    }
  }
  __syncthreads();

  // ---- softmax: wave w = batch w, lanes 0-18 = agents (width-32 tree)
  if (!isV && lane < 32) {
    const int bb = wave, j = lane;      // batch, agent
    float s = -1e30f;
    if (j < 19) {
      int row = j * 4 + bb;             // interleaved: row = agent*4 + batch
      s = (spart[row] + spart[80 + row] + spart[160 + row] + spart[240 + row]) * 0.0625f;
    }
    float mx = s;
#pragma unroll
    for (int off = 16; off >= 1; off >>= 1) mx = fmaxf(mx, __shfl_xor(mx, off, 32));
    float e = (j < 19) ? __expf(s - mx) : 0.f;
    float sum = e;
#pragma unroll
    for (int off = 16; off >= 1; off >>= 1) sum += __shfl_xor(sum, off, 32);
    float inv = 1.f / sum;
    float a = e * inv;
    if (j < 20) attl[j * 4 + bb] = a;   // j==19 writes the zero pad row
    if (j < 19) att_out[(size_t)(b0 + bb) * 19 + j] = a;
  }
  __syncthreads();

  // ---- V-waves: epilogue  h = sum_rows att * relu(v + sv)
  if (isV) {
    float svreg[4][4];
#pragma unroll
    for (int c = 0; c < 4; ++c) {
      int col = (4 * kvw + c) * 16 + m;
#pragma unroll
      for (int r = 0; r < 4; ++r) svreg[c][r] = (float)svl16[r * 256 + col];
    }
    float hacc[4][4];   // [c][batch==r]
#pragma unroll
    for (int c = 0; c < 4; ++c)
#pragma unroll
      for (int r = 0; r < 4; ++r) hacc[c][r] = 0.f;
#pragma unroll
    for (int rt = 0; rt < 5; ++rt) {
      float av[4];
#pragma unroll
      for (int r = 0; r < 4; ++r) av[r] = attl[rt * 16 + quad * 4 + r];
#pragma unroll
      for (int c = 0; c < 4; ++c) {
#pragma unroll
        for (int r = 0; r < 4; ++r) {
          float v = acc[rt][c][r] + svreg[c][r];
          v = v > 0.f ? v : 0.f;
          hacc[c][r] += v * av[r];
        }
      }
    }
#pragma unroll
    for (int c = 0; c < 4; ++c)
#pragma unroll
      for (int r = 0; r < 4; ++r) {
        float h = hacc[c][r];
        h += __shfl_xor(h, 16, 64);
        h += __shfl_xor(h, 32, 64);
        if (quad == 0) qh16[r * 256 + (4 * kvw + c) * 16 + m] = (bf16)h;
      }
  }
  __syncthreads();
  ((unsigned*)(hb + (size_t)b0 * 256))[tid] = ((const unsigned*)qh16)[tid];
}

// ---------------------------------------------------------------------------
extern "C" void kernel_launch(void* const* d_in, const int* in_sizes, int n_in,
                              void* d_out, int out_size, void* d_ws, size_t ws_size,
                              hipStream_t stream) {
  (void)in_sizes; (void)n_in; (void)out_size; (void)ws_size;
  const float* x      = (const float*)d_in[0];
  const float* eps    = (const float*)d_in[1];
  const float* W_mu   = (const float*)d_in[2];
  const float* b_mu   = (const float*)d_in[3];
  const float* W_var  = (const float*)d_in[4];
  const float* b_var  = (const float*)d_in[5];
  const float* W_self = (const float*)d_in[6];
  const float* b_self = (const float*)d_in[7];
  const float* W_other= (const float*)d_in[8];
  const float* b_other= (const float*)d_in[9];
  const float* W_q    = (const float*)d_in[10];
  const float* b_q    = (const float*)d_in[11];
  const float* W_k    = (const float*)d_in[12];
  const float* b_k    = (const float*)d_in[13];
  const float* W_v    = (const float*)d_in[14];
  const float* b_v    = (const float*)d_in[15];
  const float* W_a    = (const float*)d_in[16];
  const float* b_a    = (const float*)d_in[17];

  char* wsb = (char*)d_ws;
  bf16* WtMu    = (bf16*)(wsb + OFF_WT_MU);
  bf16* WtVar   = (bf16*)(wsb + OFF_WT_VAR);
  bf16* WtSelf  = (bf16*)(wsb + OFF_WT_SELF);
  bf16* WtOther = (bf16*)(wsb + OFF_WT_OTHER);
  bf16* WtQ     = (bf16*)(wsb + OFF_WT_Q);
  bf16* WtK     = (bf16*)(wsb + OFF_WT_K);
  bf16* WtV1    = (bf16*)(wsb + OFF_WT_V1);
  bf16* WtV2    = (bf16*)(wsb + OFF_WT_V2);
  bf16* WtA1    = (bf16*)(wsb + OFF_WT_A1);
  bf16* WtA2    = (bf16*)(wsb + OFF_WT_A2);
  bf16* zbuf    = (bf16*)(wsb + OFF_Z);
  bf16* selfbuf = (bf16*)(wsb + OFF_SELF);
  bf16* qbuf    = (bf16*)(wsb + OFF_Q);
  bf16* svbuf   = (bf16*)(wsb + OFF_SV);
  bf16* hbuf    = (bf16*)(wsb + OFF_H);

  float* out = (float*)d_out;
  float* att_out = out + (size_t)NB * 256;

  dim3 blk(256);
  wprep<<<dim3(160, 10), blk, 0, stream>>>(W_mu, W_var, W_self, W_other, W_q, W_k, W_v, W_a, wsb);
  // z = eps*exp(0.5*logvar)+mu  AND  self_em = relu(x@W_self+b), one launch
  gemm_zself<<<dim3(NB / 64, 4), blk, 0, stream>>>(x, WtMu, WtVar, WtSelf,
                                                   b_mu, b_var, b_self, eps, zbuf, selfbuf);
  // q = relu(z@W_q+b_q)  AND  sv = self_em@W_v[256:]+b_v, one launch (async)
  gemm_qsv<<<dim3(NB / 64, 4), blk, 0, stream>>>(zbuf, selfbuf, WtQ, WtV2,
                                                 b_q, b_v, qbuf, svbuf);
  // fused: other_em -> [k | v] unified GEMM -> scores -> softmax -> h
  k_fused<<<NB / 4, dim3(512), 0, stream>>>(x, qbuf, svbuf, WtOther, b_other, WtK, b_k,
                                            WtV1, att_out, hbuf);
  // out = relu([h; self_em] @ W_a + b_a)   (dual-A, async staged)
  gemm_dualA<<<dim3(NB / 64, 2), blk, 0, stream>>>(hbuf, selfbuf, WtA1, WtA2, b_a, out);
}